// Round 1
// baseline (103.830 us; speedup 1.0000x reference)
//
#include <hip/hip_runtime.h>
#include <hip/hip_bf16.h>

#define TPB 256
#define NEXPERT 64

// ---------------------------------------------------------------------------
// K1: per-chunk expert histogram. counts laid out as counts[e * NB + b] so a
// flat exclusive scan yields stable counting-sort bases (expert-major, then
// chunk, then in-chunk original order == stable argsort by expert).
// ---------------------------------------------------------------------------
__global__ void k_hist(const int* __restrict__ expert, int NK, int NB,
                       int* __restrict__ counts) {
    __shared__ int h[NEXPERT];
    const int b = blockIdx.x;
    for (int e = threadIdx.x; e < NEXPERT; e += blockDim.x) h[e] = 0;
    __syncthreads();
    const int i = b * TPB + threadIdx.x;
    if (i < NK) atomicAdd(&h[expert[i]], 1);
    __syncthreads();
    for (int e = threadIdx.x; e < NEXPERT; e += blockDim.x)
        counts[e * NB + b] = h[e];
}

// ---------------------------------------------------------------------------
// K2: single-block exclusive prefix scan over M = NEXPERT*NB ints (M=4096).
// Each of 1024 threads owns ipt consecutive elements; Hillis-Steele over the
// per-thread sums in LDS.
// ---------------------------------------------------------------------------
__global__ void k_scan(int* __restrict__ counts, int M) {
    __shared__ int s[1024];
    const int t = threadIdx.x;
    const int nt = blockDim.x;
    const int ipt = (M + nt - 1) / nt;      // elements per thread (4 here)
    int v[8];                               // ipt <= 8 assumed
    int sum = 0;
    for (int j = 0; j < ipt; ++j) {
        const int idx = t * ipt + j;
        v[j] = (idx < M) ? counts[idx] : 0;
        sum += v[j];
    }
    s[t] = sum;
    __syncthreads();
    // inclusive Hillis-Steele scan over per-thread sums
    for (int off = 1; off < nt; off <<= 1) {
        const int x = (t >= off) ? s[t - off] : 0;
        __syncthreads();
        s[t] += x;
        __syncthreads();
    }
    int base = (t == 0) ? 0 : s[t - 1];     // exclusive base for this thread
    for (int j = 0; j < ipt; ++j) {
        const int idx = t * ipt + j;
        const int c = v[j];
        if (idx < M) counts[idx] = base;
        base += c;
    }
}

// ---------------------------------------------------------------------------
// K3: stable scatter. Recompute in-chunk stable rank (count of earlier
// same-expert elements in this chunk, via LDS), then
//   dst = base[e*NB + b] + rank.
// Writes:
//   out_expert[dst] = e            (as float32)
//   out_row[row]    = dst          (inverse permutation, as float32)
//   token_of_dst[dst] = row % N    (workspace, drives the gather)
// ---------------------------------------------------------------------------
__global__ void k_scatter(const int* __restrict__ expert,
                          const int* __restrict__ rowi,
                          int NK, int NB, int N,
                          const int* __restrict__ base,
                          float* __restrict__ out_row,
                          float* __restrict__ out_expert,
                          int* __restrict__ token_of_dst) {
    __shared__ int se[TPB];
    const int b = blockIdx.x;
    const int i = b * TPB + threadIdx.x;
    int e = -1;
    if (i < NK) e = expert[i];
    se[threadIdx.x] = e;
    __syncthreads();
    if (i < NK) {
        int rank = 0;
        for (int j = 0; j < threadIdx.x; ++j) rank += (se[j] == e);
        const int dst = base[e * NB + b] + rank;
        const int r = rowi[i];
        out_expert[dst] = (float)e;
        out_row[r] = (float)dst;
        token_of_dst[dst] = r % N;
    }
}

// ---------------------------------------------------------------------------
// K4: the heavy kernel — gather x rows into sorted order. One block per
// output row; float4 (16 B/lane) coalesced copy. H=4096 -> 1024 float4s,
// 4 iters per thread at 256 threads.
// ---------------------------------------------------------------------------
__global__ void k_gather(const float* __restrict__ x,
                         const int* __restrict__ token_of_dst,
                         float* __restrict__ out_x, int H) {
    const int row = blockIdx.x;
    const int tok = token_of_dst[row];
    const float4* __restrict__ src =
        (const float4*)(x + (size_t)tok * (size_t)H);
    float4* __restrict__ dst = (float4*)(out_x + (size_t)row * (size_t)H);
    const int n4 = H >> 2;
    for (int j = threadIdx.x; j < n4; j += blockDim.x) dst[j] = src[j];
}

extern "C" void kernel_launch(void* const* d_in, const int* in_sizes, int n_in,
                              void* d_out, int out_size, void* d_ws, size_t ws_size,
                              hipStream_t stream) {
    const float* x    = (const float*)d_in[0];  // [N, H] fp32
    const int*   rowi = (const int*)d_in[1];    // [N, K] int32
    const int*   expi = (const int*)d_in[2];    // [N, K] int32
    // d_in[3] = active_num (scalar) — implied by sizes, unused

    const int NK = in_sizes[1];                    // N*K = 16384
    const int H  = (out_size - 2 * NK) / NK;       // 4096
    const int N  = in_sizes[0] / H;                // 8192
    const int NB = (NK + TPB - 1) / TPB;           // 64 chunks

    // Output layout (all float32): [NK*H] expanded_x | [NK] row_idx | [NK] expert_idx
    float* out_x      = (float*)d_out;
    float* out_row    = out_x + (size_t)NK * (size_t)H;
    float* out_expert = out_row + NK;

    // Workspace: counts/bases [64*NB] ints, then token_of_dst [NK] ints.
    int* counts = (int*)d_ws;
    int* token  = counts + NEXPERT * NB;

    k_hist   <<<NB, TPB, 0, stream>>>(expi, NK, NB, counts);
    k_scan   <<<1, 1024, 0, stream>>>(counts, NEXPERT * NB);
    k_scatter<<<NB, TPB, 0, stream>>>(expi, rowi, NK, NB, N, counts,
                                      out_row, out_expert, token);
    k_gather <<<NK, TPB, 0, stream>>>(x, token, out_x, H);
}

// Round 2
// 77.075 us; speedup vs baseline: 1.3471x; 1.3471x over previous
//
#include <hip/hip_runtime.h>
#include <hip/hip_bf16.h>

#define TPB 256
#define NEXPERT 64

typedef float f32x4 __attribute__((ext_vector_type(4)));

// ---------------------------------------------------------------------------
// K1: per-chunk expert histogram. counts laid out as counts[e * NB + b] so a
// flat exclusive scan yields stable counting-sort bases (expert-major, then
// chunk, then in-chunk original order == stable argsort by expert).
// ---------------------------------------------------------------------------
__global__ void k_hist(const int* __restrict__ expert, int NK, int NB,
                       int* __restrict__ counts) {
    __shared__ int h[NEXPERT];
    const int b = blockIdx.x;
    for (int e = threadIdx.x; e < NEXPERT; e += blockDim.x) h[e] = 0;
    __syncthreads();
    const int i = b * TPB + threadIdx.x;
    if (i < NK) atomicAdd(&h[expert[i]], 1);
    __syncthreads();
    for (int e = threadIdx.x; e < NEXPERT; e += blockDim.x)
        counts[e * NB + b] = h[e];
}

// ---------------------------------------------------------------------------
// K2: single-block exclusive prefix scan over M = NEXPERT*NB ints (M=4096).
// ---------------------------------------------------------------------------
__global__ void k_scan(int* __restrict__ counts, int M) {
    __shared__ int s[1024];
    const int t = threadIdx.x;
    const int nt = blockDim.x;
    const int ipt = (M + nt - 1) / nt;      // elements per thread (4 here)
    int v[8];                               // ipt <= 8 assumed
    int sum = 0;
    for (int j = 0; j < ipt; ++j) {
        const int idx = t * ipt + j;
        v[j] = (idx < M) ? counts[idx] : 0;
        sum += v[j];
    }
    s[t] = sum;
    __syncthreads();
    for (int off = 1; off < nt; off <<= 1) {
        const int x = (t >= off) ? s[t - off] : 0;
        __syncthreads();
        s[t] += x;
        __syncthreads();
    }
    int base = (t == 0) ? 0 : s[t - 1];     // exclusive base for this thread
    for (int j = 0; j < ipt; ++j) {
        const int idx = t * ipt + j;
        const int c = v[j];
        if (idx < M) counts[idx] = base;
        base += c;
    }
}

// ---------------------------------------------------------------------------
// K3: stable scatter with ballot-based rank.
// Within a 64-lane wave: match-mask via 7 ballots (e in [0,64], 64 = inactive
// sentinel), rank = popcount of earlier same-e lanes. Cross-wave offsets via
// per-wave per-expert counts in LDS. dst = base[e*NB+b] + rank_in_block.
// Writes:
//   out_expert[dst]  = e       (float32)
//   out_row[r]       = dst     (inverse permutation, float32)
//   dst_of_r[r]      = dst     (int workspace; r is the row VALUE, which for
//                               this problem is the flat index arange(N*K))
// ---------------------------------------------------------------------------
__global__ void k_scatter(const int* __restrict__ expert,
                          const int* __restrict__ rowi,
                          int NK, int NB,
                          const int* __restrict__ base,
                          float* __restrict__ out_row,
                          float* __restrict__ out_expert,
                          int* __restrict__ dst_of_r) {
    __shared__ int h[TPB / 64][NEXPERT + 1];
    const int b = blockIdx.x;
    const int tid = threadIdx.x;
    const int w = tid >> 6;
    const int lane = tid & 63;
    const int i = b * TPB + tid;
    const bool valid = (i < NK);
    const int e = valid ? expert[i] : NEXPERT;   // sentinel for inactive lanes

    for (int idx = tid; idx < (TPB / 64) * (NEXPERT + 1); idx += TPB)
        (&h[0][0])[idx] = 0;
    __syncthreads();

    // lanes-with-same-e mask via bitwise ballots (7 bits covers 0..64)
    unsigned long long mask = ~0ull;
#pragma unroll
    for (int bit = 0; bit < 7; ++bit) {
        const unsigned long long bv = __ballot((e >> bit) & 1);
        mask &= ((e >> bit) & 1) ? bv : ~bv;
    }
    const int rank_w = __popcll(mask & ((1ull << lane) - 1ull));
    const int cnt_w  = __popcll(mask);
    if (rank_w == 0) h[w][e] = cnt_w;   // lowest lane of each expert group
    __syncthreads();

    if (valid) {
        int rank = rank_w;
        for (int w2 = 0; w2 < w; ++w2) rank += h[w2][e];
        const int dst = base[e * NB + b] + rank;
        const int r = rowi[i];
        out_expert[dst] = (float)e;
        out_row[r] = (float)dst;
        dst_of_r[r] = dst;
    }
}

// ---------------------------------------------------------------------------
// K4: token-driven gather. Token t is consumed by flat rows {t, t+N, ...}
// (reference gathers x[r % N]). One block per token: read x[t] ONCE from HBM,
// write to all K destination rows with nontemporal float4 stores.
// Read traffic: 134 MB (vs up to 268 MB destination-driven).
// ---------------------------------------------------------------------------
template <int K>
__global__ void k_gatherT(const float* __restrict__ x,
                          const int* __restrict__ dst_of_r,
                          float* __restrict__ out_x, int H, int N) {
    const int t = blockIdx.x;
    const f32x4* __restrict__ src = (const f32x4*)(x + (size_t)t * (size_t)H);
    size_t ob[K];
#pragma unroll
    for (int kk = 0; kk < K; ++kk)
        ob[kk] = (size_t)dst_of_r[t + kk * N] * (size_t)H;
    const int n4 = H >> 2;
    for (int j = threadIdx.x; j < n4; j += blockDim.x) {
        const f32x4 v = src[j];
#pragma unroll
        for (int kk = 0; kk < K; ++kk)
            __builtin_nontemporal_store(v, (f32x4*)(out_x + ob[kk]) + j);
    }
}

// Generic-K fallback (one pass per k; re-reads src, but only used for odd K>4)
__global__ void k_gather_gen(const float* __restrict__ x,
                             const int* __restrict__ dst_of_r,
                             float* __restrict__ out_x, int H, int N, int K) {
    const int t = blockIdx.x;
    const f32x4* __restrict__ src = (const f32x4*)(x + (size_t)t * (size_t)H);
    const int n4 = H >> 2;
    for (int kk = 0; kk < K; ++kk) {
        const size_t ob = (size_t)dst_of_r[t + kk * N] * (size_t)H;
        for (int j = threadIdx.x; j < n4; j += blockDim.x)
            __builtin_nontemporal_store(src[j], (f32x4*)(out_x + ob) + j);
    }
}

extern "C" void kernel_launch(void* const* d_in, const int* in_sizes, int n_in,
                              void* d_out, int out_size, void* d_ws, size_t ws_size,
                              hipStream_t stream) {
    const float* x    = (const float*)d_in[0];  // [N, H] fp32
    const int*   rowi = (const int*)d_in[1];    // [N, K] int32 (arange)
    const int*   expi = (const int*)d_in[2];    // [N, K] int32

    const int NK = in_sizes[1];                    // N*K = 16384
    const int H  = (out_size - 2 * NK) / NK;       // 4096
    const int N  = in_sizes[0] / H;                // 8192
    const int K  = NK / N;                         // 2
    const int NB = (NK + TPB - 1) / TPB;           // 64 chunks

    // Output layout (all float32): [NK*H] expanded_x | [NK] row_idx | [NK] expert_idx
    float* out_x      = (float*)d_out;
    float* out_row    = out_x + (size_t)NK * (size_t)H;
    float* out_expert = out_row + NK;

    // Workspace: counts/bases [64*NB] ints, then dst_of_r [NK] ints.
    int* counts   = (int*)d_ws;
    int* dst_of_r = counts + NEXPERT * NB;

    k_hist   <<<NB, TPB, 0, stream>>>(expi, NK, NB, counts);
    k_scan   <<<1, 1024, 0, stream>>>(counts, NEXPERT * NB);
    k_scatter<<<NB, TPB, 0, stream>>>(expi, rowi, NK, NB, counts,
                                      out_row, out_expert, dst_of_r);

    switch (K) {
        case 1: k_gatherT<1><<<N, TPB, 0, stream>>>(x, dst_of_r, out_x, H, N); break;
        case 2: k_gatherT<2><<<N, TPB, 0, stream>>>(x, dst_of_r, out_x, H, N); break;
        case 3: k_gatherT<3><<<N, TPB, 0, stream>>>(x, dst_of_r, out_x, H, N); break;
        case 4: k_gatherT<4><<<N, TPB, 0, stream>>>(x, dst_of_r, out_x, H, N); break;
        default: k_gather_gen<<<N, TPB, 0, stream>>>(x, dst_of_r, out_x, H, N, K); break;
    }
}